// Round 1
// baseline (1262.485 us; speedup 1.0000x reference)
//
#include <hip/hip_runtime.h>
#include <hip/hip_bf16.h>
#include <cstddef>

// Problem constants (match reference)
constexpr int B = 64, T = 1024, I = 8, H = 512, O = 2;
constexpr float ALPHA = 0.2f;
constexpr float NOISE_STD = 0.05f;

// ---------------------------------------------------------------------------
// Kernel 1: precompute d[b,t,h] = NOISE_STD*noise + ALPHA * (input @ (wi*si))
// Pure memory-bound: reads 128MB noise + 2MB input, writes 128MB.
// One float4 per thread.
// ---------------------------------------------------------------------------
__global__ __launch_bounds__(256)
void precompute_d_kernel(const float* __restrict__ input,
                         const float* __restrict__ noise,
                         const float* __restrict__ wi,
                         const float* __restrict__ si,
                         float* __restrict__ d) {
    const size_t idx = (size_t)blockIdx.x * blockDim.x + threadIdx.x; // float4 index
    const size_t bt  = idx >> 7;          // / (H/4)
    const int    hq  = (int)(idx & 127) << 2;  // *4, h offset within row

    const float4 nz = *(const float4*)(noise + idx * 4);
    float4 p = make_float4(0.f, 0.f, 0.f, 0.f);
#pragma unroll
    for (int i = 0; i < I; ++i) {
        const float  x = input[bt * I + i] * si[i];
        const float4 w = *(const float4*)(wi + i * H + hq);
        p.x = fmaf(x, w.x, p.x);
        p.y = fmaf(x, w.y, p.y);
        p.z = fmaf(x, w.z, p.z);
        p.w = fmaf(x, w.w, p.w);
    }
    float4 o;
    o.x = fmaf(NOISE_STD, nz.x, ALPHA * p.x);
    o.y = fmaf(NOISE_STD, nz.y, ALPHA * p.y);
    o.z = fmaf(NOISE_STD, nz.z, ALPHA * p.z);
    o.w = fmaf(NOISE_STD, nz.w, ALPHA * p.w);
    *(float4*)(d + idx * 4) = o;
}

// ---------------------------------------------------------------------------
// Kernel 2: the sequential RNN. One wave (64 threads) per batch element.
// Lane `l` owns hidden units j = 256*k + 4*l + c, k in {0,1}, c in {0..3}
// (so each k-slot is a coalesced float4 per lane).
// FUSED=true: computes d on the fly from noise+input (fallback if ws too small)
// ---------------------------------------------------------------------------
template <bool FUSED>
__global__ __launch_bounds__(64)
void rnn_kernel(const float* __restrict__ dbuf,   // !FUSED: precomputed d ; FUSED: noise
                const float* __restrict__ input,  // FUSED only
                const float* __restrict__ wi,     // FUSED only
                const float* __restrict__ si,     // FUSED only
                const float* __restrict__ m,
                const float* __restrict__ n,
                const float* __restrict__ wo,
                const float* __restrict__ so,
                const float* __restrict__ h0,
                float* __restrict__ out,          // (B,T,O)
                float* __restrict__ traj)         // (B,T,H)
{
    const int b    = blockIdx.x;
    const int lane = threadIdx.x;   // 0..63

    constexpr float RS = ALPHA / (float)H;   // scale for recurrent term
    constexpr float OMA = 1.0f - ALPHA;

    const float so0 = so[0] / (float)H;
    const float so1 = so[1] / (float)H;

    float m0s[8], m1s[8], n0[8], n1[8], wo0s[8], wo1s[8], h[8], r[8];
    float wif[I][8];  // only used when FUSED

#pragma unroll
    for (int k = 0; k < 2; ++k) {
#pragma unroll
        for (int c = 0; c < 4; ++c) {
            const int s = k * 4 + c;
            const int j = 256 * k + 4 * lane + c;
            m0s[s]  = m[2 * j + 0] * RS;
            m1s[s]  = m[2 * j + 1] * RS;
            n0[s]   = n[2 * j + 0];
            n1[s]   = n[2 * j + 1];
            wo0s[s] = wo[2 * j + 0] * so0;
            wo1s[s] = wo[2 * j + 1] * so1;
            h[s]    = h0[j];
            r[s]    = tanhf(h[s]);
            if (FUSED) {
#pragma unroll
                for (int i = 0; i < I; ++i) wif[i][s] = wi[i * H + j] * si[i];
            }
        }
    }

    const float* pd    = dbuf + (size_t)b * T * H + 4 * lane;
    float*       ptraj = traj + (size_t)b * T * H + 4 * lane;
    const float* pin   = input + (size_t)b * T * I;  // FUSED only
    float*       pout  = out + (size_t)b * T * O;

    // software prefetch: cur holds data for step t
    float4 cur0 = *(const float4*)(pd + 0);
    float4 cur1 = *(const float4*)(pd + 256);

    for (int t = 0; t < T; ++t) {
        // ---- prefetch next step's data (off critical path) ----
        float4 nxt0, nxt1;
        if (t + 1 < T) {
            nxt0 = *(const float4*)(pd + (size_t)(t + 1) * H);
            nxt1 = *(const float4*)(pd + (size_t)(t + 1) * H + 256);
        }

        // ---- 4 dot products of r_{t-1}: a0,a1 (recurrence) + o0,o1 (out_{t-1}) ----
        float pa0 = 0.f, pa1 = 0.f, po0 = 0.f, po1 = 0.f;
#pragma unroll
        for (int s = 0; s < 8; ++s) {
            pa0 = fmaf(r[s], n0[s], pa0);
            pa1 = fmaf(r[s], n1[s], pa1);
            po0 = fmaf(r[s], wo0s[s], po0);
            po1 = fmaf(r[s], wo1s[s], po1);
        }
#pragma unroll
        for (int mk = 1; mk < 64; mk <<= 1) {
            pa0 += __shfl_xor(pa0, mk);
            pa1 += __shfl_xor(pa1, mk);
            po0 += __shfl_xor(po0, mk);
            po1 += __shfl_xor(po1, mk);
        }
        if (lane == 0 && t > 0) {
            float2 o2 = make_float2(po0, po1);
            *(float2*)(pout + (size_t)(t - 1) * O) = o2;
        }

        // ---- d values for this step ----
        float dv[8];
        if (!FUSED) {
            dv[0] = cur0.x; dv[1] = cur0.y; dv[2] = cur0.z; dv[3] = cur0.w;
            dv[4] = cur1.x; dv[5] = cur1.y; dv[6] = cur1.z; dv[7] = cur1.w;
        } else {
            float x[I];
#pragma unroll
            for (int i = 0; i < I; ++i) x[i] = pin[(size_t)t * I + i];
            const float nzv[8] = {cur0.x, cur0.y, cur0.z, cur0.w,
                                  cur1.x, cur1.y, cur1.z, cur1.w};
#pragma unroll
            for (int s = 0; s < 8; ++s) {
                float p = 0.f;
#pragma unroll
                for (int i = 0; i < I; ++i) p = fmaf(x[i], wif[i][s], p);
                dv[s] = fmaf(NOISE_STD, nzv[s], ALPHA * p);
            }
        }

        // ---- state update + tanh ----
#pragma unroll
        for (int s = 0; s < 8; ++s) {
            float tmp = fmaf(pa0, m0s[s], dv[s]);
            tmp       = fmaf(pa1, m1s[s], tmp);
            h[s]      = fmaf(h[s], OMA, tmp);
            r[s]      = tanhf(h[s]);
        }

        // ---- store trajectory (h post-update) ----
        float4 t0 = make_float4(h[0], h[1], h[2], h[3]);
        float4 t1 = make_float4(h[4], h[5], h[6], h[7]);
        *(float4*)(ptraj + (size_t)t * H + 0)   = t0;
        *(float4*)(ptraj + (size_t)t * H + 256) = t1;

        cur0 = nxt0;
        cur1 = nxt1;
    }

    // ---- final output for t = T-1 (uses r_{T-1}) ----
    float po0 = 0.f, po1 = 0.f;
#pragma unroll
    for (int s = 0; s < 8; ++s) {
        po0 = fmaf(r[s], wo0s[s], po0);
        po1 = fmaf(r[s], wo1s[s], po1);
    }
#pragma unroll
    for (int mk = 1; mk < 64; mk <<= 1) {
        po0 += __shfl_xor(po0, mk);
        po1 += __shfl_xor(po1, mk);
    }
    if (lane == 0) {
        float2 o2 = make_float2(po0, po1);
        *(float2*)(pout + (size_t)(T - 1) * O) = o2;
    }
}

// ---------------------------------------------------------------------------
extern "C" void kernel_launch(void* const* d_in, const int* in_sizes, int n_in,
                              void* d_out, int out_size, void* d_ws, size_t ws_size,
                              hipStream_t stream) {
    const float* input = (const float*)d_in[0];
    const float* noise = (const float*)d_in[1];
    const float* wi    = (const float*)d_in[2];
    const float* si    = (const float*)d_in[3];
    const float* m     = (const float*)d_in[4];
    const float* n     = (const float*)d_in[5];
    const float* wo    = (const float*)d_in[6];
    const float* so    = (const float*)d_in[7];
    const float* h0    = (const float*)d_in[8];

    float* out  = (float*)d_out;                       // (B,T,O) first
    float* traj = (float*)d_out + (size_t)B * T * O;   // then (B,T,H)

    const size_t d_bytes = (size_t)B * T * H * sizeof(float);

    if (ws_size >= d_bytes) {
        float* dbuf = (float*)d_ws;
        // 1) precompute d
        const int total4 = B * T * H / 4;  // 8388608
        precompute_d_kernel<<<total4 / 256, 256, 0, stream>>>(input, noise, wi, si, dbuf);
        // 2) sequential RNN, one wave per batch
        rnn_kernel<false><<<B, 64, 0, stream>>>(dbuf, nullptr, nullptr, nullptr,
                                                m, n, wo, so, h0, out, traj);
    } else {
        // fallback: fuse input projection into the RNN kernel
        rnn_kernel<true><<<B, 64, 0, stream>>>(noise, input, wi, si,
                                               m, n, wo, so, h0, out, traj);
    }
}

// Round 2
// 674.903 us; speedup vs baseline: 1.8706x; 1.8706x over previous
//
#include <hip/hip_runtime.h>
#include <hip/hip_bf16.h>
#include <cstddef>

// Problem constants (match reference)
constexpr int B = 64, T = 1024, I = 8, H = 512, O = 2;
constexpr float ALPHA = 0.2f;
constexpr float NOISE_STD = 0.05f;

// ---------------------------------------------------------------------------
// DPP wave-64 sum reduction: result (total of all 64 lanes) lands in lane 63.
// All-VALU (no LDS crossbar): 6 dependent v_add_f32_dpp, ~5 cyc each.
// ---------------------------------------------------------------------------
template <int CTRL>
__device__ __forceinline__ float dpp_add(float x) {
    int y = __builtin_amdgcn_update_dpp(0, __float_as_int(x), CTRL, 0xF, 0xF, true);
    return x + __int_as_float(y);
}

__device__ __forceinline__ float wave_sum_to_lane63(float x) {
    x = dpp_add<0x111>(x);  // row_shr:1
    x = dpp_add<0x112>(x);  // row_shr:2
    x = dpp_add<0x114>(x);  // row_shr:4
    x = dpp_add<0x118>(x);  // row_shr:8   -> lane 15 of each row = row sum
    x = dpp_add<0x142>(x);  // row_bcast:15
    x = dpp_add<0x143>(x);  // row_bcast:31 -> lane 63 = full sum
    return x;
}

__device__ __forceinline__ float bcast63(float x) {
    return __int_as_float(__builtin_amdgcn_readlane(__float_as_int(x), 63));
}

// Fast tanh: 1 - 2/(exp(2x)+1), via v_exp_f32 + v_rcp_f32.
// Saturates correctly: x->+inf => exp2->inf => 1; x->-inf => exp2->0 => -1.
__device__ __forceinline__ float fast_tanh(float x) {
    float z = __builtin_amdgcn_exp2f(x * 2.885390081777927f);  // e^(2x)
    return fmaf(-2.0f, __builtin_amdgcn_rcpf(z + 1.0f), 1.0f);
}

// ---------------------------------------------------------------------------
// Kernel 1: d[b,t,h] = NOISE_STD*noise + ALPHA*(input @ (wi*si))
// One block per (b,t) row: the 8 input values are blockIdx-uniform => scalar
// loads; each of 128 threads handles one float4 of H. Pure memory-bound.
// ---------------------------------------------------------------------------
__global__ __launch_bounds__(128)
void precompute_d_kernel(const float* __restrict__ input,
                         const float* __restrict__ noise,
                         const float* __restrict__ wi,
                         const float* __restrict__ si,
                         float* __restrict__ d) {
    const int    bt = blockIdx.x;           // 0 .. B*T-1
    const int    hq = threadIdx.x << 2;     // float4 offset within H

    float x[I];
#pragma unroll
    for (int i = 0; i < I; ++i) x[i] = input[(size_t)bt * I + i] * si[i];

    const size_t off = (size_t)bt * H + hq;
    const float4 nz  = *(const float4*)(noise + off);

    float4 p = make_float4(0.f, 0.f, 0.f, 0.f);
#pragma unroll
    for (int i = 0; i < I; ++i) {
        const float4 w = *(const float4*)(wi + i * H + hq);
        p.x = fmaf(x[i], w.x, p.x);
        p.y = fmaf(x[i], w.y, p.y);
        p.z = fmaf(x[i], w.z, p.z);
        p.w = fmaf(x[i], w.w, p.w);
    }
    float4 o;
    o.x = fmaf(NOISE_STD, nz.x, ALPHA * p.x);
    o.y = fmaf(NOISE_STD, nz.y, ALPHA * p.y);
    o.z = fmaf(NOISE_STD, nz.z, ALPHA * p.z);
    o.w = fmaf(NOISE_STD, nz.w, ALPHA * p.w);
    *(float4*)(d + off) = o;
}

// ---------------------------------------------------------------------------
// Kernel 2: sequential RNN. One wave per batch element. Lane l owns hidden
// units j = 256*k + 4*l + c (k in {0,1}, c in {0..3}) => two coalesced
// float4 slots per lane. DPP reductions, fast tanh, SGPR broadcast.
// ---------------------------------------------------------------------------
template <bool FUSED>
__global__ __launch_bounds__(64)
void rnn_kernel(const float* __restrict__ dbuf,   // !FUSED: precomputed d ; FUSED: noise
                const float* __restrict__ input,  // FUSED only
                const float* __restrict__ wi,     // FUSED only
                const float* __restrict__ si,     // FUSED only
                const float* __restrict__ m,
                const float* __restrict__ n,
                const float* __restrict__ wo,
                const float* __restrict__ so,
                const float* __restrict__ h0,
                float* __restrict__ out,          // (B,T,O)
                float* __restrict__ traj)         // (B,T,H)
{
    const int b    = blockIdx.x;
    const int lane = threadIdx.x;   // 0..63

    constexpr float RS  = ALPHA / (float)H;   // scale for recurrent term
    constexpr float OMA = 1.0f - ALPHA;

    const float so0 = so[0] / (float)H;
    const float so1 = so[1] / (float)H;

    float m0s[8], m1s[8], n0[8], n1[8], wo0s[8], wo1s[8], h[8], r[8];
    float wif[I][8];  // only used when FUSED

#pragma unroll
    for (int k = 0; k < 2; ++k) {
#pragma unroll
        for (int c = 0; c < 4; ++c) {
            const int s = k * 4 + c;
            const int j = 256 * k + 4 * lane + c;
            m0s[s]  = m[2 * j + 0] * RS;
            m1s[s]  = m[2 * j + 1] * RS;
            n0[s]   = n[2 * j + 0];
            n1[s]   = n[2 * j + 1];
            wo0s[s] = wo[2 * j + 0] * so0;
            wo1s[s] = wo[2 * j + 1] * so1;
            h[s]    = h0[j];
            r[s]    = tanhf(h[s]);   // once, outside the hot loop: full precision
            if (FUSED) {
#pragma unroll
                for (int i = 0; i < I; ++i) wif[i][s] = wi[i * H + j] * si[i];
            }
        }
    }

    const float* pd    = dbuf + (size_t)b * T * H + 4 * lane;
    float*       ptraj = traj + (size_t)b * T * H + 4 * lane;
    const float* pin   = input + (size_t)b * T * I;  // FUSED only
    float*       pout  = out + (size_t)b * T * O;

    // software prefetch: cur holds data for step t
    float4 cur0 = *(const float4*)(pd + 0);
    float4 cur1 = *(const float4*)(pd + 256);

    for (int t = 0; t < T; ++t) {
        // ---- prefetch next step's data (off critical path) ----
        float4 nxt0, nxt1;
        if (t + 1 < T) {
            nxt0 = *(const float4*)(pd + (size_t)(t + 1) * H);
            nxt1 = *(const float4*)(pd + (size_t)(t + 1) * H + 256);
        }

        // ---- 4 dot products of r: a0,a1 (recurrence) + o0,o1 (output) ----
        // 2-way split accumulators halve the dependent fma chain.
        float pa0a = 0.f, pa1a = 0.f, po0a = 0.f, po1a = 0.f;
        float pa0b = 0.f, pa1b = 0.f, po0b = 0.f, po1b = 0.f;
#pragma unroll
        for (int s = 0; s < 4; ++s) {
            pa0a = fmaf(r[s], n0[s], pa0a);
            pa1a = fmaf(r[s], n1[s], pa1a);
            po0a = fmaf(r[s], wo0s[s], po0a);
            po1a = fmaf(r[s], wo1s[s], po1a);
            pa0b = fmaf(r[s + 4], n0[s + 4], pa0b);
            pa1b = fmaf(r[s + 4], n1[s + 4], pa1b);
            po0b = fmaf(r[s + 4], wo0s[s + 4], po0b);
            po1b = fmaf(r[s + 4], wo1s[s + 4], po1b);
        }
        float ra0 = wave_sum_to_lane63(pa0a + pa0b);
        float ra1 = wave_sum_to_lane63(pa1a + pa1b);
        float ro0 = wave_sum_to_lane63(po0a + po0b);
        float ro1 = wave_sum_to_lane63(po1a + po1b);

        if (lane == 63 && t > 0) {
            *(float2*)(pout + (size_t)(t - 1) * O) = make_float2(ro0, ro1);
        }

        const float a0 = bcast63(ra0);   // SGPR broadcast, free in fma
        const float a1 = bcast63(ra1);

        // ---- d values for this step ----
        float dv[8];
        if (!FUSED) {
            dv[0] = cur0.x; dv[1] = cur0.y; dv[2] = cur0.z; dv[3] = cur0.w;
            dv[4] = cur1.x; dv[5] = cur1.y; dv[6] = cur1.z; dv[7] = cur1.w;
        } else {
            float x[I];
#pragma unroll
            for (int i = 0; i < I; ++i) x[i] = pin[(size_t)t * I + i];
            const float nzv[8] = {cur0.x, cur0.y, cur0.z, cur0.w,
                                  cur1.x, cur1.y, cur1.z, cur1.w};
#pragma unroll
            for (int s = 0; s < 8; ++s) {
                float p = 0.f;
#pragma unroll
                for (int i = 0; i < I; ++i) p = fmaf(x[i], wif[i][s], p);
                dv[s] = fmaf(NOISE_STD, nzv[s], ALPHA * p);
            }
        }

        // ---- state update + fast tanh ----
#pragma unroll
        for (int s = 0; s < 8; ++s) {
            float tmp = fmaf(a0, m0s[s], dv[s]);
            tmp       = fmaf(a1, m1s[s], tmp);
            h[s]      = fmaf(h[s], OMA, tmp);
            r[s]      = fast_tanh(h[s]);
        }

        // ---- store trajectory (h post-update) ----
        *(float4*)(ptraj + (size_t)t * H + 0)   = make_float4(h[0], h[1], h[2], h[3]);
        *(float4*)(ptraj + (size_t)t * H + 256) = make_float4(h[4], h[5], h[6], h[7]);

        cur0 = nxt0;
        cur1 = nxt1;
    }

    // ---- final output for t = T-1 (uses r_{T-1}) ----
    float po0 = 0.f, po1 = 0.f;
#pragma unroll
    for (int s = 0; s < 8; ++s) {
        po0 = fmaf(r[s], wo0s[s], po0);
        po1 = fmaf(r[s], wo1s[s], po1);
    }
    po0 = wave_sum_to_lane63(po0);
    po1 = wave_sum_to_lane63(po1);
    if (lane == 63) {
        *(float2*)(pout + (size_t)(T - 1) * O) = make_float2(po0, po1);
    }
}

// ---------------------------------------------------------------------------
extern "C" void kernel_launch(void* const* d_in, const int* in_sizes, int n_in,
                              void* d_out, int out_size, void* d_ws, size_t ws_size,
                              hipStream_t stream) {
    const float* input = (const float*)d_in[0];
    const float* noise = (const float*)d_in[1];
    const float* wi    = (const float*)d_in[2];
    const float* si    = (const float*)d_in[3];
    const float* m     = (const float*)d_in[4];
    const float* n     = (const float*)d_in[5];
    const float* wo    = (const float*)d_in[6];
    const float* so    = (const float*)d_in[7];
    const float* h0    = (const float*)d_in[8];

    float* out  = (float*)d_out;                       // (B,T,O) first
    float* traj = (float*)d_out + (size_t)B * T * O;   // then (B,T,H)

    const size_t d_bytes = (size_t)B * T * H * sizeof(float);

    if (ws_size >= d_bytes) {
        float* dbuf = (float*)d_ws;
        // 1) precompute d — one block per (b,t) row
        precompute_d_kernel<<<B * T, 128, 0, stream>>>(input, noise, wi, si, dbuf);
        // 2) sequential RNN, one wave per batch
        rnn_kernel<false><<<B, 64, 0, stream>>>(dbuf, nullptr, nullptr, nullptr,
                                                m, n, wo, so, h0, out, traj);
    } else {
        // fallback: fuse input projection into the RNN kernel
        rnn_kernel<true><<<B, 64, 0, stream>>>(noise, input, wi, si,
                                               m, n, wo, so, h0, out, traj);
    }
}